// Round 1
// baseline (29332.010 us; speedup 1.0000x reference)
//
#include <hip/hip_runtime.h>
#include <cstdint>
#include <cstddef>

typedef __bf16 bf16;
typedef __attribute__((ext_vector_type(8))) __bf16 bf16x8;
typedef __attribute__((ext_vector_type(4))) float f32x4;

#define DEV static __device__ __forceinline__

DEV float sigm_(float x) { return 1.f / (1.f + __expf(-x)); }
DEV float tanhf_(float x) {
  float e = __expf(-2.f * fabsf(x));
  float t = (1.f - e) / (1.f + e);
  return x < 0.f ? -t : t;
}

DEV void gload_lds16(const bf16* g, bf16* l) {
  __builtin_amdgcn_global_load_lds((const __attribute__((address_space(1))) void*)g,
                                   (__attribute__((address_space(3))) void*)l, 16, 0, 0);
}

// ---------------------------------------------------------------------------
// repack kernels (run every launch: d_ws is re-poisoned)
// ---------------------------------------------------------------------------

// frames[(t*64+b)][c<576] = (t==0 || c>=552) ? 0 : S_pad[(t-1)*64+b][c]
__global__ void k_frames(const float* __restrict__ S, bf16* __restrict__ dst) {
  int idx = blockIdx.x * 256 + threadIdx.x;
  if (idx >= 38400 * 576) return;
  int r = idx / 576, c = idx - r * 576;
  int t = r >> 6, b = r & 63;
  float v = (t == 0 || c >= 552) ? 0.f : S[((size_t)(t - 1) * 64 + b) * 552 + c];
  dst[idx] = (bf16)v;
}

// generic zero-padded 2D fp32->bf16 repack
__global__ void k_pad2d(const float* __restrict__ src, bf16* __restrict__ dst,
                        int N, int Cdst, int Csrc, int Rsrc, int sstride) {
  int idx = blockIdx.x * 256 + threadIdx.x;
  if (idx >= N) return;
  int r = idx / Cdst, c = idx - r * Cdst;
  float v = (r < Rsrc && c < Csrc) ? src[(size_t)r * sstride + c] : 0.f;
  dst[idx] = (bf16)v;
}

// W0comb[4096][1280]: k<1024 -> Whh0, k>=1024 -> Wih0[:, k-1024] (first 256 of 384; ctx part is x0)
__global__ void k_w0c(const float* __restrict__ Whh0, const float* __restrict__ Wih0,
                      bf16* __restrict__ dst) {
  int idx = blockIdx.x * 256 + threadIdx.x;
  if (idx >= 4096 * 1280) return;
  int r = idx / 1280, k = idx - r * 1280;
  float v = (k < 1024) ? Whh0[(size_t)r * 1024 + k] : Wih0[(size_t)r * 384 + (k - 1024)];
  dst[idx] = (bf16)v;
}

// W1comb[4096][2048]: k<1024 -> Wih1 (x = h0cur), k>=1024 -> Whh1 (h1prev)
__global__ void k_w1c(const float* __restrict__ Wih1, const float* __restrict__ Whh1,
                      bf16* __restrict__ dst) {
  int idx = blockIdx.x * 256 + threadIdx.x;
  if (idx >= 4096 * 2048) return;
  int r = idx / 2048, k = idx - r * 2048;
  float v = (k < 1024) ? Wih1[(size_t)r * 1024 + k] : Whh1[(size_t)r * 1024 + (k - 1024)];
  dst[idx] = (bf16)v;
}

// conv weight [Co][Ci][5] -> [Codst][5][Cpad] bf16 (zero pads)
__global__ void k_convw(const float* __restrict__ src, bf16* __restrict__ dst,
                        int N, int Cpad, int Cisrc, int Cosrc) {
  int idx = blockIdx.x * 256 + threadIdx.x;
  if (idx >= N) return;
  int per = 5 * Cpad;
  int co = idx / per, rem = idx - co * per;
  int tap = rem / Cpad, ci = rem - tap * Cpad;
  float v = (co < Cosrc && ci < Cisrc) ? src[((size_t)co * Cisrc + ci) * 5 + tap] : 0.f;
  dst[idx] = (bf16)v;
}

// ---------------------------------------------------------------------------
// generic NT GEMM: C[M,N] = A[M,Kp] * B[N,Kp]^T, bf16 inputs, fp32 acc
// tiles 128x128, BK=64, global_load_lds staging, mfma 16x16x32 bf16
// ---------------------------------------------------------------------------
enum { M_RELU = 0, M_LINEAR = 1, M_CONVT = 2, M_CONVF = 3 };

template <int MODE>
__global__ __launch_bounds__(256) void gemm_k(
    const bf16* __restrict__ A, const bf16* __restrict__ B, int Ktot, int Kstride,
    int Brows, const float* __restrict__ bias,
    bf16* __restrict__ outB, int outStride,
    float* __restrict__ outF, bf16* __restrict__ outX) {
  const int tid = threadIdx.x;
  const int lane = tid & 63, wv = tid >> 6;
  const int n0 = blockIdx.x * 128, m0 = blockIdx.y * 128;
  const int bz = blockIdx.z;
  __shared__ bf16 As[128 * 64];
  __shared__ bf16 Bs[128 * 64];
  f32x4 acc[4][4] = {};
  const int wr = wv >> 1, wc = wv & 1;
  int tap = 0, ci0 = 0;

  for (int kb = 0; kb < Ktot; kb += 64) {
    // ---- stage A tile (128 rows x 64 cols): wave wv stages rows [wv*32, wv*32+32)
#pragma unroll
    for (int j = 0; j < 4; ++j) {
      int rt = wv * 32 + j * 8 + (lane >> 3);
      const bf16* gp;
      if (MODE == M_CONVT || MODE == M_CONVF) {
        int l = m0 + rt;
        if (l > 599) l = 599;  // clamp (values unused, keeps loads in-bounds)
        gp = A + ((size_t)(bz * 604 + l + tap)) * Kstride + ci0 + (lane & 7) * 8;
      } else {
        gp = A + (size_t)(m0 + rt) * Kstride + kb + (lane & 7) * 8;
      }
      gload_lds16(gp, &As[(wv * 32 + j * 8) * 64]);
    }
    // ---- stage B tile
#pragma unroll
    for (int j = 0; j < 4; ++j) {
      int rn = n0 + wv * 32 + j * 8 + (lane >> 3);
      if (rn >= Brows) rn = Brows - 1;  // padded rows are zero
      const bf16* gp = B + (size_t)rn * Ktot + kb + (lane & 7) * 8;
      gload_lds16(gp, &Bs[(wv * 32 + j * 8) * 64]);
    }
    __syncthreads();
#pragma unroll
    for (int ks = 0; ks < 2; ++ks) {
      const int ko = ks * 32 + (lane >> 4) * 8;
      bf16x8 af[4], bfr[4];
#pragma unroll
      for (int i = 0; i < 4; ++i) {
        af[i] = *(const bf16x8*)&As[(wr * 64 + i * 16 + (lane & 15)) * 64 + ko];
        bfr[i] = *(const bf16x8*)&Bs[(wc * 64 + i * 16 + (lane & 15)) * 64 + ko];
      }
#pragma unroll
      for (int mi = 0; mi < 4; ++mi)
#pragma unroll
        for (int ni = 0; ni < 4; ++ni)
          acc[mi][ni] = __builtin_amdgcn_mfma_f32_16x16x32_bf16(af[mi], bfr[ni], acc[mi][ni], 0, 0, 0);
    }
    __syncthreads();
    ci0 += 64;
    if (ci0 == Kstride) { ci0 = 0; ++tap; }  // conv modes only (harmless otherwise)
  }

  // ---- epilogue: C/D layout col=lane&15, row=(lane>>4)*4+reg
  const int r0 = (lane >> 4) * 4, cc = lane & 15;
#pragma unroll
  for (int mi = 0; mi < 4; ++mi) {
#pragma unroll
    for (int ni = 0; ni < 4; ++ni) {
#pragma unroll
      for (int r = 0; r < 4; ++r) {
        float v = acc[mi][ni][r];
        int gr = m0 + wr * 64 + mi * 16 + r0 + r;
        int gc = n0 + wc * 64 + ni * 16 + cc;
        if (MODE == M_RELU) {
          v += bias[gc];
          v = fmaxf(v, 0.f);
          outB[(size_t)gr * outStride + gc] = (bf16)v;
        } else if (MODE == M_LINEAR) {
          if (gc < 552) {
            v += bias[gc];
            int t = gr >> 6, b = gr & 63;
            outF[(size_t)gr * 552 + gc] = v;                         // S_pred -> d_out
            outX[((size_t)b * 604 + t + 2) * 576 + gc] = (bf16)v;    // conv1 input (padded)
          }
        } else if (MODE == M_CONVT) {
          if (gr < 600) {
            v = tanhf_(v + bias[gc]);
            outB[((size_t)bz * 604 + gr + 2) * 512 + gc] = (bf16)v;
          }
        } else {  // M_CONVF: conv5, add into d_out
          if (gr < 600 && gc < 552) {
            v += bias[gc];
            float* p = outF + ((size_t)gr * 64 + bz) * 552 + gc;
            *p += v;
          }
        }
      }
    }
  }
}

// ---------------------------------------------------------------------------
// persistent 2-layer LSTM scan, 601 skewed phases, custom grid barrier.
// 256 blocks x 256 thr. block: layer = bid>>7; mh = (bid&127)>>6 (batch half);
// ub = bid&63 (16 units). wave = gate (i,f,g,o). c-state lives in registers.
// bid pairing: twins (mh=0/1, same ub) are 64 apart -> same XCD (64%8==0).
// ---------------------------------------------------------------------------
__global__ __launch_bounds__(256, 1) void lstm_k(
    const bf16* __restrict__ pre2, const bf16* __restrict__ W0, const bf16* __restrict__ W1,
    const float* __restrict__ bi0, const float* __restrict__ bh0,
    const float* __restrict__ bi1, const float* __restrict__ bh1,
    bf16* __restrict__ h0buf, bf16* __restrict__ h1buf,
    bf16* __restrict__ h1all, unsigned* __restrict__ bar) {
  const int tid = threadIdx.x, lane = tid & 63, gate = tid >> 6;
  const int bid = blockIdx.x;
  const int layer = bid >> 7, sub = bid & 127;
  const int mh = sub >> 6, ub = sub & 63;
  const int u0 = ub * 16, b0 = mh * 32;
  const int KT = layer ? 2048 : 1280;
  const bf16* W = layer ? W1 : W0;
  const float* bi = layer ? bi1 : bi0;
  const float* bh = layer ? bh1 : bh0;
  __shared__ bf16 Ach[32 * 264];     // staged A chunk [32 rows][256+8 pad]
  __shared__ float gbuf[4 * 32 * 16];
  const bf16* Brow = W + (size_t)(gate * 1024 + u0 + (lane & 15)) * KT + ((lane >> 4) * 8);
  float c0 = 0.f, c1 = 0.f;
  const int nch = KT >> 8;           // 5 (layer0) / 8 (layer1) chunks of K=256
  const int srow = tid >> 3;         // staging: row 0..31
  const int scol = (tid & 7) * 32;   // staging: 32 cols per thread
  const int bl = tid >> 3;           // cell update: batch-local row
  const int uu = (tid & 7) * 2;      // cell update: 2 consecutive units

  for (int p = 0; p <= 600; ++p) {
    const bool active = layer ? (p >= 1) : (p < 600);
    if (active) {
      const int t = layer ? p - 1 : p;
      const bf16* hA = h0buf + ((p + 1) & 1) * 65536;  // h0prev (l0) / h0cur (l1)
      const bf16* h1p = h1buf + (p & 1) * 65536;       // h1prev (l1)
      f32x4 acc0 = {0.f, 0.f, 0.f, 0.f}, acc1 = {0.f, 0.f, 0.f, 0.f};
      for (int ch = 0; ch < nch; ++ch) {
        const int kc = ch << 8;
        const int k = kc + scol;
        const bf16* src;
        if (k < 1024)      src = hA + (b0 + srow) * 1024 + k;
        else if (!layer)   src = pre2 + ((size_t)(t * 64 + b0 + srow)) * 256 + (k - 1024);
        else               src = h1p + (b0 + srow) * 1024 + (k - 1024);
#pragma unroll
        for (int i = 0; i < 4; ++i)
          *(bf16x8*)&Ach[srow * 264 + scol + i * 8] = *(const bf16x8*)(src + i * 8);
        __syncthreads();
#pragma unroll
        for (int ks = 0; ks < 8; ++ks) {
          bf16x8 bf_ = *(const bf16x8*)(Brow + kc + ks * 32);
          bf16x8 a0f = *(const bf16x8*)&Ach[(lane & 15) * 264 + ks * 32 + (lane >> 4) * 8];
          bf16x8 a1f = *(const bf16x8*)&Ach[((lane & 15) + 16) * 264 + ks * 32 + (lane >> 4) * 8];
          acc0 = __builtin_amdgcn_mfma_f32_16x16x32_bf16(a0f, bf_, acc0, 0, 0, 0);
          acc1 = __builtin_amdgcn_mfma_f32_16x16x32_bf16(a1f, bf_, acc1, 0, 0, 0);
        }
        __syncthreads();
      }
      // gates -> LDS  (C layout: col=lane&15 (unit), row=(lane>>4)*4+r (batch))
#pragma unroll
      for (int r = 0; r < 4; ++r) {
        gbuf[gate * 512 + ((lane >> 4) * 4 + r) * 16 + (lane & 15)] = acc0[r];
        gbuf[gate * 512 + (16 + (lane >> 4) * 4 + r) * 16 + (lane & 15)] = acc1[r];
      }
      __syncthreads();
      // cell update: 2 cells/thread, c persists in registers
#pragma unroll
      for (int j = 0; j < 2; ++j) {
        const int u = uu + j;
        const int gi_ = bl * 16 + u;
        const int rw = u0 + u;
        float gI = gbuf[gi_] + bi[rw] + bh[rw];
        float gF = gbuf[512 + gi_] + bi[1024 + rw] + bh[1024 + rw];
        float gG = gbuf[1024 + gi_] + bi[2048 + rw] + bh[2048 + rw];
        float gO = gbuf[1536 + gi_] + bi[3072 + rw] + bh[3072 + rw];
        float& c = j ? c1 : c0;
        c = sigm_(gF) * c + sigm_(gI) * tanhf_(gG);
        float h = sigm_(gO) * tanhf_(c);
        const int b = b0 + bl, ug = u0 + u;
        if (!layer) {
          h0buf[(p & 1) * 65536 + b * 1024 + ug] = (bf16)h;
        } else {
          h1buf[((p + 1) & 1) * 65536 + b * 1024 + ug] = (bf16)h;
          h1all[((size_t)t * 64 + b) * 1024 + ug] = (bf16)h;
        }
      }
    }
    // grid barrier (monotonic counter; acq_rel agent scope handles XCD coherence)
    if (p < 600) {
      __syncthreads();
      if (tid == 0) {
        __hip_atomic_fetch_add(bar, 1u, __ATOMIC_ACQ_REL, __HIP_MEMORY_SCOPE_AGENT);
        const unsigned tgt = 256u * (unsigned)(p + 1);
        while (__hip_atomic_load(bar, __ATOMIC_ACQUIRE, __HIP_MEMORY_SCOPE_AGENT) < tgt)
          __builtin_amdgcn_s_sleep(1);
      }
      __syncthreads();
    }
  }
}

// ---------------------------------------------------------------------------
// host
// ---------------------------------------------------------------------------
static inline unsigned gdiv(size_t n) { return (unsigned)((n + 255) / 256); }

extern "C" void kernel_launch(void* const* d_in, const int* in_sizes, int n_in,
                              void* d_out, int out_size, void* d_ws, size_t ws_size,
                              hipStream_t stream) {
  const float* S = (const float*)d_in[0];
  const float* preW1 = (const float*)d_in[1];
  const float* preb1 = (const float*)d_in[2];
  const float* preW2 = (const float*)d_in[3];
  const float* preb2 = (const float*)d_in[4];
  const float* Wih0 = (const float*)d_in[5];
  const float* Whh0 = (const float*)d_in[6];
  const float* bih0 = (const float*)d_in[7];
  const float* bhh0 = (const float*)d_in[8];
  const float* Wih1 = (const float*)d_in[9];
  const float* Whh1 = (const float*)d_in[10];
  const float* bih1 = (const float*)d_in[11];
  const float* bhh1 = (const float*)d_in[12];
  const float* linW = (const float*)d_in[13];
  const float* linb = (const float*)d_in[14];
  const float* cw1 = (const float*)d_in[15];
  const float* cb1 = (const float*)d_in[16];
  const float* cw2 = (const float*)d_in[17];
  const float* cb2 = (const float*)d_in[18];
  const float* cw3 = (const float*)d_in[19];
  const float* cb3 = (const float*)d_in[20];
  const float* cw4 = (const float*)d_in[21];
  const float* cb4 = (const float*)d_in[22];
  const float* cw5 = (const float*)d_in[23];
  const float* cb5 = (const float*)d_in[24];
  float* out = (float*)d_out;

  char* ws = (char*)d_ws;
  size_t off = 0;
  auto alloc = [&](size_t bytes) -> char* {
    char* p = ws + off;
    off += (bytes + 255) & ~(size_t)255;
    return p;
  };
  unsigned* bar = (unsigned*)alloc(256);
  bf16* h0b = (bf16*)alloc(2ull * 64 * 1024 * 2);
  bf16* h1b = (bf16*)alloc(2ull * 64 * 1024 * 2);
  size_t zeroBytes = off;  // bar + h buffers
  bf16* frames = (bf16*)alloc(38400ull * 576 * 2);
  bf16* pre1 = (bf16*)alloc(38400ull * 256 * 2);
  bf16* pre2 = (bf16*)alloc(38400ull * 256 * 2);
  bf16* h1all = (bf16*)alloc(38400ull * 1024 * 2);
  bf16* W0c = (bf16*)alloc(4096ull * 1280 * 2);
  bf16* W1c = (bf16*)alloc(4096ull * 2048 * 2);
  bf16* pW1b = (bf16*)alloc(256ull * 576 * 2);
  bf16* pW2b = (bf16*)alloc(256ull * 256 * 2);
  bf16* linWb = (bf16*)alloc(576ull * 1024 * 2);
  bf16* c1r = (bf16*)alloc(512ull * 5 * 576 * 2);
  bf16* c2r = (bf16*)alloc(512ull * 5 * 512 * 2);
  bf16* c3r = (bf16*)alloc(512ull * 5 * 512 * 2);
  bf16* c4r = (bf16*)alloc(512ull * 5 * 512 * 2);
  bf16* c5r = (bf16*)alloc(576ull * 5 * 512 * 2);
  bf16* X0 = (bf16*)alloc(64ull * 604 * 576 * 2);
  bf16* X1 = (bf16*)alloc(64ull * 604 * 512 * 2);
  bf16* X2 = (bf16*)alloc(64ull * 604 * 512 * 2);
  size_t xBytes = (64ull * 604 * 576 + 2ull * 64 * 604 * 512) * 2;

  // zero: barrier + h-state, and conv pad rows/cols (ws is poisoned each launch)
  hipMemsetAsync(ws, 0, zeroBytes, stream);
  hipMemsetAsync(X0, 0, xBytes, stream);

  // repacks (fp32 -> padded bf16)
  k_frames<<<gdiv(38400ull * 576), 256, 0, stream>>>(S, frames);
  k_pad2d<<<gdiv(256 * 576), 256, 0, stream>>>(preW1, pW1b, 256 * 576, 576, 552, 256, 552);
  k_pad2d<<<gdiv(256 * 256), 256, 0, stream>>>(preW2, pW2b, 256 * 256, 256, 256, 256, 256);
  k_pad2d<<<gdiv(576 * 1024), 256, 0, stream>>>(linW, linWb, 576 * 1024, 1024, 1024, 552, 1152);
  k_w0c<<<gdiv(4096ull * 1280), 256, 0, stream>>>(Whh0, Wih0, W0c);
  k_w1c<<<gdiv(4096ull * 2048), 256, 0, stream>>>(Wih1, Whh1, W1c);
  k_convw<<<gdiv(512ull * 5 * 576), 256, 0, stream>>>(cw1, c1r, 512 * 5 * 576, 576, 552, 512);
  k_convw<<<gdiv(512ull * 5 * 512), 256, 0, stream>>>(cw2, c2r, 512 * 5 * 512, 512, 512, 512);
  k_convw<<<gdiv(512ull * 5 * 512), 256, 0, stream>>>(cw3, c3r, 512 * 5 * 512, 512, 512, 512);
  k_convw<<<gdiv(512ull * 5 * 512), 256, 0, stream>>>(cw4, c4r, 512 * 5 * 512, 512, 512, 512);
  k_convw<<<gdiv(576ull * 5 * 512), 256, 0, stream>>>(cw5, c5r, 576 * 5 * 512, 512, 512, 552);

  // prenet: relu(frames @ W1^T + b1), relu(. @ W2^T + b2)
  gemm_k<M_RELU><<<dim3(2, 300, 1), 256, 0, stream>>>(frames, pW1b, 576, 576, 256, preb1,
                                                      pre1, 256, nullptr, nullptr);
  gemm_k<M_RELU><<<dim3(2, 300, 1), 256, 0, stream>>>(pre1, pW2b, 256, 256, 256, preb2,
                                                      pre2, 256, nullptr, nullptr);
  // sequential 2-layer LSTM (persistent, 256 blocks)
  lstm_k<<<dim3(256), 256, 0, stream>>>(pre2, W0c, W1c, bih0, bhh0, bih1, bhh1,
                                        h0b, h1b, h1all, bar);
  // S_pred = h1all @ linW[:, :1024]^T + lin_b  -> d_out (fp32) + X0 (bf16, conv layout)
  gemm_k<M_LINEAR><<<dim3(5, 300, 1), 256, 0, stream>>>(h1all, linWb, 1024, 1024, 576, linb,
                                                        nullptr, 0, out, X0);
  // postnet
  gemm_k<M_CONVT><<<dim3(4, 5, 64), 256, 0, stream>>>(X0, c1r, 2880, 576, 512, cb1,
                                                      X1, 0, nullptr, nullptr);
  gemm_k<M_CONVT><<<dim3(4, 5, 64), 256, 0, stream>>>(X1, c2r, 2560, 512, 512, cb2,
                                                      X2, 0, nullptr, nullptr);
  gemm_k<M_CONVT><<<dim3(4, 5, 64), 256, 0, stream>>>(X2, c3r, 2560, 512, 512, cb3,
                                                      X1, 0, nullptr, nullptr);
  gemm_k<M_CONVT><<<dim3(4, 5, 64), 256, 0, stream>>>(X1, c4r, 2560, 512, 512, cb4,
                                                      X2, 0, nullptr, nullptr);
  gemm_k<M_CONVF><<<dim3(5, 5, 64), 256, 0, stream>>>(X2, c5r, 2560, 512, 576, cb5,
                                                      nullptr, 0, out, nullptr);
  (void)in_sizes; (void)n_in; (void)out_size; (void)ws_size;
}

// Round 2
// 8574.545 us; speedup vs baseline: 3.4208x; 3.4208x over previous
//
#include <hip/hip_runtime.h>
#include <cstdint>
#include <cstddef>

typedef __bf16 bf16;
typedef __attribute__((ext_vector_type(8))) __bf16 bf16x8;
typedef __attribute__((ext_vector_type(4))) float f32x4;

#define DEV static __device__ __forceinline__

DEV float sigm_(float x) { return 1.f / (1.f + __expf(-x)); }
DEV float tanhf_(float x) {
  float e = __expf(-2.f * fabsf(x));
  float t = (1.f - e) / (1.f + e);
  return x < 0.f ? -t : t;
}

DEV void gload_lds16(const bf16* g, bf16* l) {
  __builtin_amdgcn_global_load_lds((const __attribute__((address_space(1))) void*)g,
                                   (__attribute__((address_space(3))) void*)l, 16, 0, 0);
}

// ---------------------------------------------------------------------------
// repack kernels
// ---------------------------------------------------------------------------
__global__ void k_frames(const float* __restrict__ S, bf16* __restrict__ dst) {
  int idx = blockIdx.x * 256 + threadIdx.x;
  if (idx >= 38400 * 576) return;
  int r = idx / 576, c = idx - r * 576;
  int t = r >> 6, b = r & 63;
  float v = (t == 0 || c >= 552) ? 0.f : S[((size_t)(t - 1) * 64 + b) * 552 + c];
  dst[idx] = (bf16)v;
}

__global__ void k_pad2d(const float* __restrict__ src, bf16* __restrict__ dst,
                        int N, int Cdst, int Csrc, int Rsrc, int sstride) {
  int idx = blockIdx.x * 256 + threadIdx.x;
  if (idx >= N) return;
  int r = idx / Cdst, c = idx - r * Cdst;
  float v = (r < Rsrc && c < Csrc) ? src[(size_t)r * sstride + c] : 0.f;
  dst[idx] = (bf16)v;
}

__global__ void k_w0c(const float* __restrict__ Whh0, const float* __restrict__ Wih0,
                      bf16* __restrict__ dst) {
  int idx = blockIdx.x * 256 + threadIdx.x;
  if (idx >= 4096 * 1280) return;
  int r = idx / 1280, k = idx - r * 1280;
  float v = (k < 1024) ? Whh0[(size_t)r * 1024 + k] : Wih0[(size_t)r * 384 + (k - 1024)];
  dst[idx] = (bf16)v;
}

__global__ void k_w1c(const float* __restrict__ Wih1, const float* __restrict__ Whh1,
                      bf16* __restrict__ dst) {
  int idx = blockIdx.x * 256 + threadIdx.x;
  if (idx >= 4096 * 2048) return;
  int r = idx / 2048, k = idx - r * 2048;
  float v = (k < 1024) ? Wih1[(size_t)r * 1024 + k] : Whh1[(size_t)r * 1024 + (k - 1024)];
  dst[idx] = (bf16)v;
}

__global__ void k_convw(const float* __restrict__ src, bf16* __restrict__ dst,
                        int N, int Cpad, int Cisrc, int Cosrc) {
  int idx = blockIdx.x * 256 + threadIdx.x;
  if (idx >= N) return;
  int per = 5 * Cpad;
  int co = idx / per, rem = idx - co * per;
  int tap = rem / Cpad, ci = rem - tap * Cpad;
  float v = (co < Cosrc && ci < Cisrc) ? src[((size_t)co * Cisrc + ci) * 5 + tap] : 0.f;
  dst[idx] = (bf16)v;
}

// zero pad rows {0,1,602,603} of X0[64][604][576], X1/X2[64][604][512]
__global__ void k_zpad(bf16* __restrict__ X0, bf16* __restrict__ X1, bf16* __restrict__ X2) {
  int idx = blockIdx.x * 256 + threadIdx.x;
  if (idx >= 64 * 4 * 1600) return;
  int per = 4 * 1600;
  int b = idx / per, rem = idx - b * per;
  int rr = rem / 1600, c = rem - rr * 1600;
  int row = (rr < 2) ? rr : 600 + rr;
  if (c < 576) X0[((size_t)b * 604 + row) * 576 + c] = (bf16)0.f;
  else if (c < 1088) X1[((size_t)b * 604 + row) * 512 + (c - 576)] = (bf16)0.f;
  else X2[((size_t)b * 604 + row) * 512 + (c - 1088)] = (bf16)0.f;
}

// ---------------------------------------------------------------------------
// generic NT GEMM (unchanged structure from R1)
// ---------------------------------------------------------------------------
enum { M_RELU = 0, M_LINEAR = 1, M_CONVT = 2, M_CONVF = 3 };

template <int MODE>
__global__ __launch_bounds__(256) void gemm_k(
    const bf16* __restrict__ A, const bf16* __restrict__ B, int Ktot, int Kstride,
    int Brows, const float* __restrict__ bias,
    bf16* __restrict__ outB, int outStride, int colP, int colOff,
    float* __restrict__ outF, bf16* __restrict__ outX) {
  const int tid = threadIdx.x;
  const int lane = tid & 63, wv = tid >> 6;
  const int n0 = blockIdx.x * 128, m0 = blockIdx.y * 128;
  const int bz = blockIdx.z;
  __shared__ bf16 As[128 * 64];
  __shared__ bf16 Bs[128 * 64];
  f32x4 acc[4][4] = {};
  const int wr = wv >> 1, wc = wv & 1;
  int tap = 0, ci0 = 0;

  for (int kb = 0; kb < Ktot; kb += 64) {
#pragma unroll
    for (int j = 0; j < 4; ++j) {
      int rt = wv * 32 + j * 8 + (lane >> 3);
      const bf16* gp;
      if (MODE == M_CONVT || MODE == M_CONVF) {
        int l = m0 + rt;
        if (l > 599) l = 599;
        gp = A + ((size_t)(bz * 604 + l + tap)) * Kstride + ci0 + (lane & 7) * 8;
      } else {
        gp = A + (size_t)(m0 + rt) * Kstride + kb + (lane & 7) * 8;
      }
      gload_lds16(gp, &As[(wv * 32 + j * 8) * 64]);
    }
#pragma unroll
    for (int j = 0; j < 4; ++j) {
      int rn = n0 + wv * 32 + j * 8 + (lane >> 3);
      if (rn >= Brows) rn = Brows - 1;
      const bf16* gp = B + (size_t)rn * Ktot + kb + (lane & 7) * 8;
      gload_lds16(gp, &Bs[(wv * 32 + j * 8) * 64]);
    }
    __syncthreads();
#pragma unroll
    for (int ks = 0; ks < 2; ++ks) {
      const int ko = ks * 32 + (lane >> 4) * 8;
      bf16x8 af[4], bfr[4];
#pragma unroll
      for (int i = 0; i < 4; ++i) {
        af[i] = *(const bf16x8*)&As[(wr * 64 + i * 16 + (lane & 15)) * 64 + ko];
        bfr[i] = *(const bf16x8*)&Bs[(wc * 64 + i * 16 + (lane & 15)) * 64 + ko];
      }
#pragma unroll
      for (int mi = 0; mi < 4; ++mi)
#pragma unroll
        for (int ni = 0; ni < 4; ++ni)
          acc[mi][ni] = __builtin_amdgcn_mfma_f32_16x16x32_bf16(af[mi], bfr[ni], acc[mi][ni], 0, 0, 0);
    }
    __syncthreads();
    ci0 += 64;
    if (ci0 == Kstride) { ci0 = 0; ++tap; }
  }

  const int r0 = (lane >> 4) * 4, cc = lane & 15;
#pragma unroll
  for (int mi = 0; mi < 4; ++mi) {
#pragma unroll
    for (int ni = 0; ni < 4; ++ni) {
#pragma unroll
      for (int r = 0; r < 4; ++r) {
        float v = acc[mi][ni][r];
        int gr = m0 + wr * 64 + mi * 16 + r0 + r;
        int gc = n0 + wc * 64 + ni * 16 + cc;
        if (MODE == M_RELU) {
          v += bias[gc];
          v = fmaxf(v, 0.f);
          outB[(size_t)(gr >> 6) * outStride + (size_t)(gr & 63) * colP + colOff + gc] = (bf16)v;
        } else if (MODE == M_LINEAR) {
          if (gc < 552) {
            v += bias[gc];
            int t = gr >> 6, b = gr & 63;
            outF[(size_t)gr * 552 + gc] = v;
            outX[((size_t)b * 604 + t + 2) * 576 + gc] = (bf16)v;
          }
        } else if (MODE == M_CONVT) {
          if (gr < 600) {
            v = tanhf_(v + bias[gc]);
            outB[((size_t)bz * 604 + gr + 2) * 512 + gc] = (bf16)v;
          }
        } else {
          if (gr < 600 && gc < 552) {
            v += bias[gc];
            float* p = outF + ((size_t)gr * 64 + bz) * 552 + gc;
            *p += v;
          }
        }
      }
    }
  }
}

// ---------------------------------------------------------------------------
// persistent 2-layer LSTM scan v2: weights in registers, k-split 4 waves,
// relaxed-spin barrier + single acquire fence/phase, phase-unique h addresses.
// C0[601][64][1280]: [0:1024)=h0[t-1] (row0=0), [1024:1280)=pre2[t]
// H1[602][64][1024]: h1[t] at row t+2 (rows 0,1 = 0)
// 256 blocks: layer=bid>>7, mh=(bid&127)>>6 (batch half 32), ub=bid&63 (16 units)
// ---------------------------------------------------------------------------
template <int LAYER>
DEV void scan_impl(bf16* __restrict__ C0, bf16* __restrict__ H1,
                   const bf16* __restrict__ W, const float* __restrict__ bi,
                   const float* __restrict__ bh, unsigned* __restrict__ bar,
                   bf16* As, float* gb, int u0, int b0) {
  constexpr int KT = LAYER ? 2048 : 1280;
  constexpr int NKS = LAYER ? 16 : 10;   // k-steps of 32 per wave slice
  constexpr int S = LAYER ? 2056 : 1288; // LDS row stride (K + 8: conflict-free b128)
  const int tid = threadIdx.x;
  const int lane = tid & 63, w = tid >> 6;
  const int kb = w * (KT / 4);

  // B fragments (64 gate-rows x K/4) -> registers, loaded once
  bf16x8 wreg[4][NKS];
#pragma unroll
  for (int gi = 0; gi < 4; ++gi)
#pragma unroll
    for (int ks = 0; ks < NKS; ++ks)
      wreg[gi][ks] = *(const bf16x8*)(W + (size_t)(gi * 1024 + u0 + (lane & 15)) * KT +
                                      kb + ks * 32 + (lane >> 4) * 8);

  const int bl = tid >> 3, uu = (tid & 7) * 2;
  float bs[4][2];
#pragma unroll
  for (int g = 0; g < 4; ++g)
#pragma unroll
    for (int j = 0; j < 2; ++j) {
      int rw = g * 1024 + u0 + uu + j;
      bs[g][j] = bi[rw] + bh[rw];
    }
  float cst[2] = {0.f, 0.f};

  for (int p = 0; p <= 600; ++p) {
    const bool active = LAYER ? (p >= 1) : (p < 600);
    if (active) {
      // ---- stage A [32 rows x K] via global_load_lds (wave w: rows w*8..w*8+7)
      bf16* xrow = C0 + (size_t)p * 81920;
#pragma unroll
      for (int j = 0; j < 8; ++j) {
        const int rr = w * 8 + j;
        const bf16* src = xrow + (size_t)(b0 + rr) * 1280;
        gload_lds16(src + lane * 8, &As[rr * S]);
        gload_lds16(src + 512 + lane * 8, &As[rr * S + 512]);
        if (LAYER) {
          const bf16* src2 = H1 + (size_t)p * 65536 + (size_t)(b0 + rr) * 1024;
          gload_lds16(src2 + lane * 8, &As[rr * S + 1024]);
          gload_lds16(src2 + 512 + lane * 8, &As[rr * S + 1536]);
        }
      }
      if (!LAYER) {  // pre2 part: 8 rows x 256 elems via VGPR roundtrip
        const int jr = lane >> 3, e = lane & 7;
        const int rr = w * 8 + jr;
        const bf16* src = xrow + (size_t)(b0 + rr) * 1280 + 1024 + e * 32;
#pragma unroll
        for (int i = 0; i < 4; ++i)
          *(bf16x8*)&As[rr * S + 1024 + e * 32 + i * 8] = *(const bf16x8*)(src + i * 8);
      }
      __syncthreads();
      // ---- MFMA: 8 independent chains (4 gates x 2 batch-16s), B from registers
      f32x4 acc[4][2] = {};
#pragma unroll
      for (int ks = 0; ks < NKS; ++ks) {
        const int col = kb + ks * 32 + (lane >> 4) * 8;
        bf16x8 a0 = *(const bf16x8*)&As[(lane & 15) * S + col];
        bf16x8 a1 = *(const bf16x8*)&As[((lane & 15) + 16) * S + col];
#pragma unroll
        for (int gi = 0; gi < 4; ++gi) {
          acc[gi][0] = __builtin_amdgcn_mfma_f32_16x16x32_bf16(a0, wreg[gi][ks], acc[gi][0], 0, 0, 0);
          acc[gi][1] = __builtin_amdgcn_mfma_f32_16x16x32_bf16(a1, wreg[gi][ks], acc[gi][1], 0, 0, 0);
        }
      }
      __syncthreads();  // gb aliases As
      // ---- write k-partials: gb[(w*4+gi)*16+unit][batch(33)]
      const int un = lane & 15, qb = (lane >> 4) * 4;
#pragma unroll
      for (int gi = 0; gi < 4; ++gi)
#pragma unroll
        for (int b2 = 0; b2 < 2; ++b2)
#pragma unroll
          for (int r = 0; r < 4; ++r)
            gb[((w * 4 + gi) * 16 + un) * 33 + b2 * 16 + qb + r] = acc[gi][b2][r];
      __syncthreads();
      // ---- cell update: thread = (batch bl, units uu..uu+1), c in registers
      float hv[2];
#pragma unroll
      for (int j = 0; j < 2; ++j) {
        const int u = uu + j;
        float s[4];
#pragma unroll
        for (int g = 0; g < 4; ++g) {
          float t = 0.f;
#pragma unroll
          for (int ww = 0; ww < 4; ++ww) t += gb[((ww * 4 + g) * 16 + u) * 33 + bl];
          s[g] = t + bs[g][j];
        }
        float c = sigm_(s[1]) * cst[j] + sigm_(s[0]) * tanhf_(s[2]);
        cst[j] = c;
        hv[j] = sigm_(s[3]) * tanhf_(c);
      }
      union { bf16 h2[2]; unsigned u32; } pk;
      pk.h2[0] = (bf16)hv[0];
      pk.h2[1] = (bf16)hv[1];
      unsigned* dst =
          LAYER ? (unsigned*)(H1 + (size_t)(p + 1) * 65536 + (size_t)(b0 + bl) * 1024 + u0 + uu)
                : (unsigned*)(C0 + (size_t)(p + 1) * 81920 + (size_t)(b0 + bl) * 1280 + u0 + uu);
      __hip_atomic_store(dst, pk.u32, __ATOMIC_RELAXED, __HIP_MEMORY_SCOPE_AGENT);
    }
    if (p < 600) {
      asm volatile("s_waitcnt vmcnt(0)" ::: "memory");  // per-wave: h stores at coherent point
      __syncthreads();
      if (tid == 0) {
        __hip_atomic_fetch_add(bar, 1u, __ATOMIC_RELAXED, __HIP_MEMORY_SCOPE_AGENT);
        const unsigned tgt = 256u * (unsigned)(p + 1);
        while (__hip_atomic_load(bar, __ATOMIC_RELAXED, __HIP_MEMORY_SCOPE_AGENT) < tgt)
          __builtin_amdgcn_s_sleep(2);
        __builtin_amdgcn_fence(__ATOMIC_ACQUIRE, "agent");  // one L2 inv per phase
      }
      __syncthreads();
    }
  }
}

__global__ __launch_bounds__(256, 1) void lstm_k(
    bf16* __restrict__ C0, bf16* __restrict__ H1,
    const bf16* __restrict__ W0, const bf16* __restrict__ W1,
    const float* __restrict__ bi0, const float* __restrict__ bh0,
    const float* __restrict__ bi1, const float* __restrict__ bh1,
    unsigned* __restrict__ bar) {
  __shared__ __align__(16) char smem[131584];  // As (32 x 2056 bf16) / gb (16x16x33 f32) alias
  bf16* As = (bf16*)smem;
  float* gb = (float*)smem;
  const int bid = blockIdx.x;
  const int layer = bid >> 7, sub = bid & 127;
  const int u0 = (sub & 63) * 16, b0 = (sub >> 6) * 32;
  if (layer == 0)
    scan_impl<0>(C0, H1, W0, bi0, bh0, bar, As, gb, u0, b0);
  else
    scan_impl<1>(C0, H1, W1, bi1, bh1, bar, As, gb, u0, b0);
}

// ---------------------------------------------------------------------------
// host
// ---------------------------------------------------------------------------
static inline unsigned gdiv(size_t n) { return (unsigned)((n + 255) / 256); }

extern "C" void kernel_launch(void* const* d_in, const int* in_sizes, int n_in,
                              void* d_out, int out_size, void* d_ws, size_t ws_size,
                              hipStream_t stream) {
  const float* S = (const float*)d_in[0];
  const float* preW1 = (const float*)d_in[1];
  const float* preb1 = (const float*)d_in[2];
  const float* preW2 = (const float*)d_in[3];
  const float* preb2 = (const float*)d_in[4];
  const float* Wih0 = (const float*)d_in[5];
  const float* Whh0 = (const float*)d_in[6];
  const float* bih0 = (const float*)d_in[7];
  const float* bhh0 = (const float*)d_in[8];
  const float* Wih1 = (const float*)d_in[9];
  const float* Whh1 = (const float*)d_in[10];
  const float* bih1 = (const float*)d_in[11];
  const float* bhh1 = (const float*)d_in[12];
  const float* linW = (const float*)d_in[13];
  const float* linb = (const float*)d_in[14];
  const float* cw1 = (const float*)d_in[15];
  const float* cb1 = (const float*)d_in[16];
  const float* cw2 = (const float*)d_in[17];
  const float* cb2 = (const float*)d_in[18];
  const float* cw3 = (const float*)d_in[19];
  const float* cb3 = (const float*)d_in[20];
  const float* cw4 = (const float*)d_in[21];
  const float* cb4 = (const float*)d_in[22];
  const float* cw5 = (const float*)d_in[23];
  const float* cb5 = (const float*)d_in[24];
  float* out = (float*)d_out;

  char* ws = (char*)d_ws;
  size_t off = 0;
  auto alloc = [&](size_t bytes) -> char* {
    char* p = ws + off;
    off += (bytes + 255) & ~(size_t)255;
    return p;
  };
  unsigned* bar = (unsigned*)alloc(256);
  bf16* H1 = (bf16*)alloc(602ull * 64 * 1024 * 2);
  bf16* frames = (bf16*)alloc(38400ull * 576 * 2);
  bf16* pre1 = (bf16*)alloc(38400ull * 256 * 2);
  bf16* W0c = (bf16*)alloc(4096ull * 1280 * 2);
  bf16* W1c = (bf16*)alloc(4096ull * 2048 * 2);
  bf16* pW1b = (bf16*)alloc(256ull * 576 * 2);
  bf16* pW2b = (bf16*)alloc(256ull * 256 * 2);
  bf16* linWb = (bf16*)alloc(576ull * 1024 * 2);
  bf16* c1r = (bf16*)alloc(512ull * 5 * 576 * 2);
  bf16* c2r = (bf16*)alloc(512ull * 5 * 512 * 2);
  bf16* c3r = (bf16*)alloc(512ull * 5 * 512 * 2);
  bf16* c4r = (bf16*)alloc(512ull * 5 * 512 * 2);
  bf16* c5r = (bf16*)alloc(576ull * 5 * 512 * 2);
  bf16* X0 = (bf16*)alloc(64ull * 604 * 576 * 2);
  bf16* X1 = (bf16*)alloc(64ull * 604 * 512 * 2);
  bf16* X2 = (bf16*)alloc(64ull * 604 * 512 * 2);
  bf16* C0 = X0;  // C0[601][64][1280] aliases X0..X2 (dead until after lstm)

  // zero: barrier + H1 rows 0,1 ; C0 row 0
  hipMemsetAsync(ws, 0, 256 + 2ull * 64 * 1024 * 2, stream);
  hipMemsetAsync(C0, 0, 64ull * 1280 * 2, stream);

  // repacks
  k_frames<<<gdiv(38400ull * 576), 256, 0, stream>>>(S, frames);
  k_pad2d<<<gdiv(256 * 576), 256, 0, stream>>>(preW1, pW1b, 256 * 576, 576, 552, 256, 552);
  k_pad2d<<<gdiv(256 * 256), 256, 0, stream>>>(preW2, pW2b, 256 * 256, 256, 256, 256, 256);
  k_pad2d<<<gdiv(576 * 1024), 256, 0, stream>>>(linW, linWb, 576 * 1024, 1024, 1024, 552, 1152);
  k_w0c<<<gdiv(4096ull * 1280), 256, 0, stream>>>(Whh0, Wih0, W0c);
  k_w1c<<<gdiv(4096ull * 2048), 256, 0, stream>>>(Wih1, Whh1, W1c);
  k_convw<<<gdiv(512ull * 5 * 576), 256, 0, stream>>>(cw1, c1r, 512 * 5 * 576, 576, 552, 512);
  k_convw<<<gdiv(512ull * 5 * 512), 256, 0, stream>>>(cw2, c2r, 512 * 5 * 512, 512, 512, 512);
  k_convw<<<gdiv(512ull * 5 * 512), 256, 0, stream>>>(cw3, c3r, 512 * 5 * 512, 512, 512, 512);
  k_convw<<<gdiv(512ull * 5 * 512), 256, 0, stream>>>(cw4, c4r, 512 * 5 * 512, 512, 512, 512);
  k_convw<<<gdiv(576ull * 5 * 512), 256, 0, stream>>>(cw5, c5r, 576 * 5 * 512, 512, 512, 552);

  // prenet: pre1 = relu(frames@W1^T+b1); C0[t][b][1024:1280] = relu(pre1@W2^T+b2)
  gemm_k<M_RELU><<<dim3(2, 300, 1), 256, 0, stream>>>(frames, pW1b, 576, 576, 256, preb1,
                                                      pre1, 16384, 256, 0, nullptr, nullptr);
  gemm_k<M_RELU><<<dim3(2, 300, 1), 256, 0, stream>>>(pre1, pW2b, 256, 256, 256, preb2,
                                                      C0, 81920, 1280, 1024, nullptr, nullptr);
  // sequential 2-layer LSTM (persistent, 256 blocks, register weights)
  lstm_k<<<dim3(256), 256, 0, stream>>>(C0, H1, W0c, W1c, bih0, bhh0, bih1, bhh1, bar);
  // zero conv pad rows (X bufs were aliased by C0)
  k_zpad<<<gdiv(64 * 4 * 1600), 256, 0, stream>>>(X0, X1, X2);
  // S_pred = h1 @ linW^T + lin_b ; h1[t*64+b] = H1 + 2*64*1024 offset
  gemm_k<M_LINEAR><<<dim3(5, 300, 1), 256, 0, stream>>>(H1 + 131072, linWb, 1024, 1024, 576, linb,
                                                        nullptr, 0, 0, 0, out, X0);
  // postnet
  gemm_k<M_CONVT><<<dim3(4, 5, 64), 256, 0, stream>>>(X0, c1r, 2880, 576, 512, cb1,
                                                      X1, 0, 0, 0, nullptr, nullptr);
  gemm_k<M_CONVT><<<dim3(4, 5, 64), 256, 0, stream>>>(X1, c2r, 2560, 512, 512, cb2,
                                                      X2, 0, 0, 0, nullptr, nullptr);
  gemm_k<M_CONVT><<<dim3(4, 5, 64), 256, 0, stream>>>(X2, c3r, 2560, 512, 512, cb3,
                                                      X1, 0, 0, 0, nullptr, nullptr);
  gemm_k<M_CONVT><<<dim3(4, 5, 64), 256, 0, stream>>>(X1, c4r, 2560, 512, 512, cb4,
                                                      X2, 0, 0, 0, nullptr, nullptr);
  gemm_k<M_CONVF><<<dim3(5, 5, 64), 256, 0, stream>>>(X2, c5r, 2560, 512, 576, cb5,
                                                      nullptr, 0, 0, 0, out, nullptr);
  (void)in_sizes; (void)n_in; (void)out_size; (void)ws_size;
}

// Round 3
// 7627.025 us; speedup vs baseline: 3.8458x; 1.1242x over previous
//
#include <hip/hip_runtime.h>
#include <cstdint>
#include <cstddef>

typedef __bf16 bf16;
typedef __attribute__((ext_vector_type(8))) __bf16 bf16x8;
typedef __attribute__((ext_vector_type(4))) float f32x4;

#define DEV static __device__ __forceinline__

DEV float sigm_(float x) { return 1.f / (1.f + __expf(-x)); }
DEV float tanhf_(float x) {
  float e = __expf(-2.f * fabsf(x));
  float t = (1.f - e) / (1.f + e);
  return x < 0.f ? -t : t;
}

DEV void gload_lds16(const bf16* g, bf16* l) {
  __builtin_amdgcn_global_load_lds((const __attribute__((address_space(1))) void*)g,
                                   (__attribute__((address_space(3))) void*)l, 16, 0, 0);
}

// ---------------------------------------------------------------------------
// repack kernels
// ---------------------------------------------------------------------------
__global__ void k_frames(const float* __restrict__ S, bf16* __restrict__ dst) {
  int idx = blockIdx.x * 256 + threadIdx.x;
  if (idx >= 38400 * 576) return;
  int r = idx / 576, c = idx - r * 576;
  int t = r >> 6, b = r & 63;
  float v = (t == 0 || c >= 552) ? 0.f : S[((size_t)(t - 1) * 64 + b) * 552 + c];
  dst[idx] = (bf16)v;
}

__global__ void k_pad2d(const float* __restrict__ src, bf16* __restrict__ dst,
                        int N, int Cdst, int Csrc, int Rsrc, int sstride) {
  int idx = blockIdx.x * 256 + threadIdx.x;
  if (idx >= N) return;
  int r = idx / Cdst, c = idx - r * Cdst;
  float v = (r < Rsrc && c < Csrc) ? src[(size_t)r * sstride + c] : 0.f;
  dst[idx] = (bf16)v;
}

__global__ void k_w0c(const float* __restrict__ Whh0, const float* __restrict__ Wih0,
                      bf16* __restrict__ dst) {
  int idx = blockIdx.x * 256 + threadIdx.x;
  if (idx >= 4096 * 1280) return;
  int r = idx / 1280, k = idx - r * 1280;
  float v = (k < 1024) ? Whh0[(size_t)r * 1024 + k] : Wih0[(size_t)r * 384 + (k - 1024)];
  dst[idx] = (bf16)v;
}

__global__ void k_w1c(const float* __restrict__ Wih1, const float* __restrict__ Whh1,
                      bf16* __restrict__ dst) {
  int idx = blockIdx.x * 256 + threadIdx.x;
  if (idx >= 4096 * 2048) return;
  int r = idx / 2048, k = idx - r * 2048;
  float v = (k < 1024) ? Wih1[(size_t)r * 1024 + k] : Whh1[(size_t)r * 1024 + (k - 1024)];
  dst[idx] = (bf16)v;
}

__global__ void k_convw(const float* __restrict__ src, bf16* __restrict__ dst,
                        int N, int Cpad, int Cisrc, int Cosrc) {
  int idx = blockIdx.x * 256 + threadIdx.x;
  if (idx >= N) return;
  int per = 5 * Cpad;
  int co = idx / per, rem = idx - co * per;
  int tap = rem / Cpad, ci = rem - tap * Cpad;
  float v = (co < Cosrc && ci < Cisrc) ? src[((size_t)co * Cisrc + ci) * 5 + tap] : 0.f;
  dst[idx] = (bf16)v;
}

// zero pad rows {0,1,602,603} of X0[64][604][576], X1/X2[64][604][512]
__global__ void k_zpad(bf16* __restrict__ X0, bf16* __restrict__ X1, bf16* __restrict__ X2) {
  int idx = blockIdx.x * 256 + threadIdx.x;
  if (idx >= 64 * 4 * 1600) return;
  int per = 4 * 1600;
  int b = idx / per, rem = idx - b * per;
  int rr = rem / 1600, c = rem - rr * 1600;
  int row = (rr < 2) ? rr : 600 + rr;
  if (c < 576) X0[((size_t)b * 604 + row) * 576 + c] = (bf16)0.f;
  else if (c < 1088) X1[((size_t)b * 604 + row) * 512 + (c - 576)] = (bf16)0.f;
  else X2[((size_t)b * 604 + row) * 512 + (c - 1088)] = (bf16)0.f;
}

// ---------------------------------------------------------------------------
// generic NT GEMM (unchanged from R2)
// ---------------------------------------------------------------------------
enum { M_RELU = 0, M_LINEAR = 1, M_CONVT = 2, M_CONVF = 3 };

template <int MODE>
__global__ __launch_bounds__(256) void gemm_k(
    const bf16* __restrict__ A, const bf16* __restrict__ B, int Ktot, int Kstride,
    int Brows, const float* __restrict__ bias,
    bf16* __restrict__ outB, int outStride, int colP, int colOff,
    float* __restrict__ outF, bf16* __restrict__ outX) {
  const int tid = threadIdx.x;
  const int lane = tid & 63, wv = tid >> 6;
  const int n0 = blockIdx.x * 128, m0 = blockIdx.y * 128;
  const int bz = blockIdx.z;
  __shared__ bf16 As[128 * 64];
  __shared__ bf16 Bs[128 * 64];
  f32x4 acc[4][4] = {};
  const int wr = wv >> 1, wc = wv & 1;
  int tap = 0, ci0 = 0;

  for (int kb = 0; kb < Ktot; kb += 64) {
#pragma unroll
    for (int j = 0; j < 4; ++j) {
      int rt = wv * 32 + j * 8 + (lane >> 3);
      const bf16* gp;
      if (MODE == M_CONVT || MODE == M_CONVF) {
        int l = m0 + rt;
        if (l > 599) l = 599;
        gp = A + ((size_t)(bz * 604 + l + tap)) * Kstride + ci0 + (lane & 7) * 8;
      } else {
        gp = A + (size_t)(m0 + rt) * Kstride + kb + (lane & 7) * 8;
      }
      gload_lds16(gp, &As[(wv * 32 + j * 8) * 64]);
    }
#pragma unroll
    for (int j = 0; j < 4; ++j) {
      int rn = n0 + wv * 32 + j * 8 + (lane >> 3);
      if (rn >= Brows) rn = Brows - 1;
      const bf16* gp = B + (size_t)rn * Ktot + kb + (lane & 7) * 8;
      gload_lds16(gp, &Bs[(wv * 32 + j * 8) * 64]);
    }
    __syncthreads();
#pragma unroll
    for (int ks = 0; ks < 2; ++ks) {
      const int ko = ks * 32 + (lane >> 4) * 8;
      bf16x8 af[4], bfr[4];
#pragma unroll
      for (int i = 0; i < 4; ++i) {
        af[i] = *(const bf16x8*)&As[(wr * 64 + i * 16 + (lane & 15)) * 64 + ko];
        bfr[i] = *(const bf16x8*)&Bs[(wc * 64 + i * 16 + (lane & 15)) * 64 + ko];
      }
#pragma unroll
      for (int mi = 0; mi < 4; ++mi)
#pragma unroll
        for (int ni = 0; ni < 4; ++ni)
          acc[mi][ni] = __builtin_amdgcn_mfma_f32_16x16x32_bf16(af[mi], bfr[ni], acc[mi][ni], 0, 0, 0);
    }
    __syncthreads();
    ci0 += 64;
    if (ci0 == Kstride) { ci0 = 0; ++tap; }
  }

  const int r0 = (lane >> 4) * 4, cc = lane & 15;
#pragma unroll
  for (int mi = 0; mi < 4; ++mi) {
#pragma unroll
    for (int ni = 0; ni < 4; ++ni) {
#pragma unroll
      for (int r = 0; r < 4; ++r) {
        float v = acc[mi][ni][r];
        int gr = m0 + wr * 64 + mi * 16 + r0 + r;
        int gc = n0 + wc * 64 + ni * 16 + cc;
        if (MODE == M_RELU) {
          v += bias[gc];
          v = fmaxf(v, 0.f);
          outB[(size_t)(gr >> 6) * outStride + (size_t)(gr & 63) * colP + colOff + gc] = (bf16)v;
        } else if (MODE == M_LINEAR) {
          if (gc < 552) {
            v += bias[gc];
            int t = gr >> 6, b = gr & 63;
            outF[(size_t)gr * 552 + gc] = v;
            outX[((size_t)b * 604 + t + 2) * 576 + gc] = (bf16)v;
          }
        } else if (MODE == M_CONVT) {
          if (gr < 600) {
            v = tanhf_(v + bias[gc]);
            outB[((size_t)bz * 604 + gr + 2) * 512 + gc] = (bf16)v;
          }
        } else {
          if (gr < 600 && gc < 552) {
            v += bias[gc];
            float* p = outF + ((size_t)gr * 64 + bz) * 552 + gc;
            *p += v;
          }
        }
      }
    }
  }
}

// ---------------------------------------------------------------------------
// LSTM scan v3: flag-based group sync (no atomic RMW), direct-to-VGPR A loads
// (no LDS staging), L0 groups free-run, L1 groups chase via producer flags.
// C0[601][64][1280]: [0:1024)=h0[t-1] (row0=0), [1024:1280)=pre2[t]
// H1[602][64][1024]: h1[t] at row t+2 (rows 0,1 = 0)
// groups: g = layer*2 + mh (64 blocks each). flags[g][64] =步 counter.
// block: 16 units (ub) x 32 batch (mh). wave w = k-slice KT/4. LDS = gate
// partials only (256 rows x 36 f32).
// ---------------------------------------------------------------------------
template <int LAYER>
DEV void scan_impl(bf16* __restrict__ C0, bf16* __restrict__ H1,
                   const bf16* __restrict__ W, const float* __restrict__ bi,
                   const float* __restrict__ bh, unsigned* __restrict__ flags,
                   float* gb, int u0, int b0, int mh, int ub) {
  constexpr int KT = LAYER ? 2048 : 1280;
  constexpr int NKS = LAYER ? 16 : 10;
  const int tid = threadIdx.x, lane = tid & 63, w = tid >> 6;
  const int kb = w * (KT / 4);

  // weight B-fragments -> registers/AGPRs, loaded once
  bf16x8 wreg[4][NKS];
#pragma unroll
  for (int gi = 0; gi < 4; ++gi)
#pragma unroll
    for (int ks = 0; ks < NKS; ++ks)
      wreg[gi][ks] = *(const bf16x8*)(W + (size_t)(gi * 1024 + u0 + (lane & 15)) * KT +
                                      kb + ks * 32 + (lane >> 4) * 8);

  const int bl = tid >> 3, uu = (tid & 7) * 2;
  float bs[4][2];
#pragma unroll
  for (int g = 0; g < 4; ++g)
#pragma unroll
    for (int j = 0; j < 2; ++j) {
      int rw = g * 1024 + u0 + uu + j;
      bs[g][j] = bi[rw] + bh[rw];
    }
  float cst[2] = {0.f, 0.f};

  unsigned* flO = flags + (LAYER * 2 + mh) * 64;
  unsigned* flP = flags + mh * 64;  // L0 group, same batch half

  const int r0 = lane & 15, q8 = (lane >> 4) * 8;

  for (int t = 0; t < 600; ++t) {
    // ---- wait for inputs (wave 0 polls; others park at barrier)
    if (w == 0 && (LAYER || t > 0)) {
      const unsigned tO = (unsigned)t, tP = (unsigned)(t + 1);
      for (;;) {
        bool bad = __hip_atomic_load(&flO[lane], __ATOMIC_RELAXED, __HIP_MEMORY_SCOPE_AGENT) < tO;
        if (LAYER)
          bad |= __hip_atomic_load(&flP[lane], __ATOMIC_RELAXED, __HIP_MEMORY_SCOPE_AGENT) < tP;
        if (!__ballot(bad)) break;
        __builtin_amdgcn_s_sleep(1);
      }
      __builtin_amdgcn_fence(__ATOMIC_ACQUIRE, "agent");  // invalidate L2 once/phase
    }
    __syncthreads();

    // ---- A fragments straight from global (16 rows x 64B segments, coalesced)
    const bf16* A0;
    int RS;
    if (!LAYER) {
      RS = 1280;
      A0 = C0 + (size_t)t * 81920 + (size_t)(b0 + r0) * 1280 + kb + q8;
    } else if (w < 2) {
      RS = 1280;
      A0 = C0 + (size_t)(t + 1) * 81920 + (size_t)(b0 + r0) * 1280 + w * 512 + q8;
    } else {
      RS = 1024;
      A0 = H1 + (size_t)(t + 1) * 65536 + (size_t)(b0 + r0) * 1024 + (w - 2) * 512 + q8;
    }
    const bf16* A1 = A0 + 16 * RS;

    f32x4 acc[4][2] = {};
#pragma unroll
    for (int ks = 0; ks < NKS; ++ks) {
      bf16x8 a0 = *(const bf16x8*)(A0 + ks * 32);
      bf16x8 a1 = *(const bf16x8*)(A1 + ks * 32);
#pragma unroll
      for (int gi = 0; gi < 4; ++gi) {
        acc[gi][0] = __builtin_amdgcn_mfma_f32_16x16x32_bf16(a0, wreg[gi][ks], acc[gi][0], 0, 0, 0);
        acc[gi][1] = __builtin_amdgcn_mfma_f32_16x16x32_bf16(a1, wreg[gi][ks], acc[gi][1], 0, 0, 0);
      }
    }

    // ---- k-partials to LDS: row = (w*4+gi)*16 + unit, col = batch-local (stride 36)
    const int un = lane & 15, qb = (lane >> 4) * 4;
#pragma unroll
    for (int gi = 0; gi < 4; ++gi)
#pragma unroll
      for (int b2 = 0; b2 < 2; ++b2)
        *(f32x4*)&gb[((w * 4 + gi) * 16 + un) * 36 + b2 * 16 + qb] = acc[gi][b2];
    __syncthreads();

    // ---- cell update: thread = (batch bl 0..31, units uu..uu+1), c in regs
    float hv[2];
#pragma unroll
    for (int j = 0; j < 2; ++j) {
      const int u = uu + j;
      float s[4];
#pragma unroll
      for (int g = 0; g < 4; ++g) {
        float acc_s = 0.f;
#pragma unroll
        for (int ww = 0; ww < 4; ++ww) acc_s += gb[((ww * 4 + g) * 16 + u) * 36 + bl];
        s[g] = acc_s + bs[g][j];
      }
      float c = sigm_(s[1]) * cst[j] + sigm_(s[0]) * tanhf_(s[2]);
      cst[j] = c;
      hv[j] = sigm_(s[3]) * tanhf_(c);
    }
    union { bf16 h2[2]; unsigned u32; } pk;
    pk.h2[0] = (bf16)hv[0];
    pk.h2[1] = (bf16)hv[1];
    unsigned* dst =
        LAYER ? (unsigned*)(H1 + (size_t)(t + 2) * 65536 + (size_t)(b0 + bl) * 1024 + u0 + uu)
              : (unsigned*)(C0 + (size_t)(t + 1) * 81920 + (size_t)(b0 + bl) * 1280 + u0 + uu);
    __hip_atomic_store(dst, pk.u32, __ATOMIC_RELAXED, __HIP_MEMORY_SCOPE_AGENT);
    asm volatile("s_waitcnt vmcnt(0)" ::: "memory");  // own h-stores at coherence point
    __syncthreads();                                   // all block's h-stores done
    if (tid == 0)
      __hip_atomic_store(&flO[ub], (unsigned)(t + 1), __ATOMIC_RELAXED, __HIP_MEMORY_SCOPE_AGENT);
  }
}

__global__ __launch_bounds__(256, 1) void lstm_k(
    bf16* __restrict__ C0, bf16* __restrict__ H1,
    const bf16* __restrict__ W0, const bf16* __restrict__ W1,
    const float* __restrict__ bi0, const float* __restrict__ bh0,
    const float* __restrict__ bi1, const float* __restrict__ bh1,
    unsigned* __restrict__ flags) {
  __shared__ float gb[256 * 36];  // 36.9 KB gate partials
  const int bid = blockIdx.x;
  const int layer = bid >> 7, sub = bid & 127;
  const int mh = sub >> 6, ub = sub & 63;
  const int u0 = ub * 16, b0 = mh * 32;
  if (layer == 0)
    scan_impl<0>(C0, H1, W0, bi0, bh0, flags, gb, u0, b0, mh, ub);
  else
    scan_impl<1>(C0, H1, W1, bi1, bh1, flags, gb, u0, b0, mh, ub);
}

// ---------------------------------------------------------------------------
// host
// ---------------------------------------------------------------------------
static inline unsigned gdiv(size_t n) { return (unsigned)((n + 255) / 256); }

extern "C" void kernel_launch(void* const* d_in, const int* in_sizes, int n_in,
                              void* d_out, int out_size, void* d_ws, size_t ws_size,
                              hipStream_t stream) {
  const float* S = (const float*)d_in[0];
  const float* preW1 = (const float*)d_in[1];
  const float* preb1 = (const float*)d_in[2];
  const float* preW2 = (const float*)d_in[3];
  const float* preb2 = (const float*)d_in[4];
  const float* Wih0 = (const float*)d_in[5];
  const float* Whh0 = (const float*)d_in[6];
  const float* bih0 = (const float*)d_in[7];
  const float* bhh0 = (const float*)d_in[8];
  const float* Wih1 = (const float*)d_in[9];
  const float* Whh1 = (const float*)d_in[10];
  const float* bih1 = (const float*)d_in[11];
  const float* bhh1 = (const float*)d_in[12];
  const float* linW = (const float*)d_in[13];
  const float* linb = (const float*)d_in[14];
  const float* cw1 = (const float*)d_in[15];
  const float* cb1 = (const float*)d_in[16];
  const float* cw2 = (const float*)d_in[17];
  const float* cb2 = (const float*)d_in[18];
  const float* cw3 = (const float*)d_in[19];
  const float* cb3 = (const float*)d_in[20];
  const float* cw4 = (const float*)d_in[21];
  const float* cb4 = (const float*)d_in[22];
  const float* cw5 = (const float*)d_in[23];
  const float* cb5 = (const float*)d_in[24];
  float* out = (float*)d_out;

  char* ws = (char*)d_ws;
  size_t off = 0;
  auto alloc = [&](size_t bytes) -> char* {
    char* p = ws + off;
    off += (bytes + 255) & ~(size_t)255;
    return p;
  };
  unsigned* flags = (unsigned*)alloc(1024);  // 4 groups x 64 flags
  bf16* H1 = (bf16*)alloc(602ull * 64 * 1024 * 2);
  bf16* frames = (bf16*)alloc(38400ull * 576 * 2);
  bf16* pre1 = (bf16*)alloc(38400ull * 256 * 2);
  bf16* W0c = (bf16*)alloc(4096ull * 1280 * 2);
  bf16* W1c = (bf16*)alloc(4096ull * 2048 * 2);
  bf16* pW1b = (bf16*)alloc(256ull * 576 * 2);
  bf16* pW2b = (bf16*)alloc(256ull * 256 * 2);
  bf16* linWb = (bf16*)alloc(576ull * 1024 * 2);
  bf16* c1r = (bf16*)alloc(512ull * 5 * 576 * 2);
  bf16* c2r = (bf16*)alloc(512ull * 5 * 512 * 2);
  bf16* c3r = (bf16*)alloc(512ull * 5 * 512 * 2);
  bf16* c4r = (bf16*)alloc(512ull * 5 * 512 * 2);
  bf16* c5r = (bf16*)alloc(576ull * 5 * 512 * 2);
  bf16* X0 = (bf16*)alloc(64ull * 604 * 576 * 2);
  bf16* X1 = (bf16*)alloc(64ull * 604 * 512 * 2);
  bf16* X2 = (bf16*)alloc(64ull * 604 * 512 * 2);
  bf16* C0 = X0;  // C0[601][64][1280] aliases X0..X2 (dead until after lstm)

  // zero: flags + H1 rows 0,1 ; C0 row 0
  hipMemsetAsync(ws, 0, 1024 + 2ull * 64 * 1024 * 2, stream);
  hipMemsetAsync(C0, 0, 64ull * 1280 * 2, stream);

  // repacks
  k_frames<<<gdiv(38400ull * 576), 256, 0, stream>>>(S, frames);
  k_pad2d<<<gdiv(256 * 576), 256, 0, stream>>>(preW1, pW1b, 256 * 576, 576, 552, 256, 552);
  k_pad2d<<<gdiv(256 * 256), 256, 0, stream>>>(preW2, pW2b, 256 * 256, 256, 256, 256, 256);
  k_pad2d<<<gdiv(576 * 1024), 256, 0, stream>>>(linW, linWb, 576 * 1024, 1024, 1024, 552, 1152);
  k_w0c<<<gdiv(4096ull * 1280), 256, 0, stream>>>(Whh0, Wih0, W0c);
  k_w1c<<<gdiv(4096ull * 2048), 256, 0, stream>>>(Wih1, Whh1, W1c);
  k_convw<<<gdiv(512ull * 5 * 576), 256, 0, stream>>>(cw1, c1r, 512 * 5 * 576, 576, 552, 512);
  k_convw<<<gdiv(512ull * 5 * 512), 256, 0, stream>>>(cw2, c2r, 512 * 5 * 512, 512, 512, 512);
  k_convw<<<gdiv(512ull * 5 * 512), 256, 0, stream>>>(cw3, c3r, 512 * 5 * 512, 512, 512, 512);
  k_convw<<<gdiv(512ull * 5 * 512), 256, 0, stream>>>(cw4, c4r, 512 * 5 * 512, 512, 512, 512);
  k_convw<<<gdiv(576ull * 5 * 512), 256, 0, stream>>>(cw5, c5r, 576 * 5 * 512, 512, 512, 552);

  // prenet: pre1 = relu(frames@W1^T+b1); C0[t][b][1024:1280] = relu(pre1@W2^T+b2)
  gemm_k<M_RELU><<<dim3(2, 300, 1), 256, 0, stream>>>(frames, pW1b, 576, 576, 256, preb1,
                                                      pre1, 16384, 256, 0, nullptr, nullptr);
  gemm_k<M_RELU><<<dim3(2, 300, 1), 256, 0, stream>>>(pre1, pW2b, 256, 256, 256, preb2,
                                                      C0, 81920, 1280, 1024, nullptr, nullptr);
  // sequential 2-layer LSTM (persistent, 256 blocks, flag-synced groups)
  lstm_k<<<dim3(256), 256, 0, stream>>>(C0, H1, W0c, W1c, bih0, bhh0, bih1, bhh1, flags);
  // zero conv pad rows (X bufs were aliased by C0)
  k_zpad<<<gdiv(64 * 4 * 1600), 256, 0, stream>>>(X0, X1, X2);
  // S_pred = h1 @ linW^T + lin_b ; h1[t*64+b] = H1 + 2*64*1024 offset
  gemm_k<M_LINEAR><<<dim3(5, 300, 1), 256, 0, stream>>>(H1 + 131072, linWb, 1024, 1024, 576, linb,
                                                        nullptr, 0, 0, 0, out, X0);
  // postnet
  gemm_k<M_CONVT><<<dim3(4, 5, 64), 256, 0, stream>>>(X0, c1r, 2880, 576, 512, cb1,
                                                      X1, 0, 0, 0, nullptr, nullptr);
  gemm_k<M_CONVT><<<dim3(4, 5, 64), 256, 0, stream>>>(X1, c2r, 2560, 512, 512, cb2,
                                                      X2, 0, 0, 0, nullptr, nullptr);
  gemm_k<M_CONVT><<<dim3(4, 5, 64), 256, 0, stream>>>(X2, c3r, 2560, 512, 512, cb3,
                                                      X1, 0, 0, 0, nullptr, nullptr);
  gemm_k<M_CONVT><<<dim3(4, 5, 64), 256, 0, stream>>>(X1, c4r, 2560, 512, 512, cb4,
                                                      X2, 0, 0, 0, nullptr, nullptr);
  gemm_k<M_CONVF><<<dim3(5, 5, 64), 256, 0, stream>>>(X2, c5r, 2560, 512, 576, cb5,
                                                      nullptr, 0, 0, 0, out, nullptr);
  (void)in_sizes; (void)n_in; (void)out_size; (void)ws_size;
}